// Round 12
// baseline (225.254 us; speedup 1.0000x reference)
//
#include <hip/hip_runtime.h>
#include <hip/hip_bf16.h>

// DIAGNOSTIC ROUND 2: exact A/B against R9's 5-pass NT diagnostic — identical
// structure (1024 blocks, 5 passes), but PLAIN stores. Measures plain-store
// steady-state rate + FETCH_SIZE for this access pattern. Output unchanged.

typedef float f4    __attribute__((ext_vector_type(4)));
typedef short s8    __attribute__((ext_vector_type(8)));   // 8 bf16 (4 VGPRs)
typedef float f32x4 __attribute__((ext_vector_type(4)));

static __device__ __forceinline__ short bf16_rne(float f) {
    unsigned u = __builtin_bit_cast(unsigned, f);
    u += 0x7FFFu + ((u >> 16) & 1u);
    return (short)(u >> 16);
}

// LDS-free MFMA GEMM: 512 blocks x 4 waves; each wave owns one 16x16 Y-tile.
__global__ __launch_bounds__(256) void gemm_mfma(const float* __restrict__ A,
                                                 const float* __restrict__ W,
                                                 float* __restrict__ Y) {
    const int tid = threadIdx.x;
    const int w = tid >> 6;          // wave 0..3
    const int l = tid & 63;
    const int rc = l & 15;           // A-row / B-col / C-col
    const int g  = l >> 4;           // k-group (8 floats each)
    const int m0 = blockIdx.x * 32 + (w >> 1) * 16;   // gridDim.x = 32
    const int o0 = blockIdx.y * 32 + (w & 1) * 16;    // gridDim.y = 16

    const float* __restrict__ ap = A + (m0 + rc) * 512 + g * 8;
    const float* __restrict__ wp = W + (o0 + rc) * 512 + g * 8;

    f32x4 acc = {0.f, 0.f, 0.f, 0.f};

    #pragma unroll 4
    for (int kk = 0; kk < 16; ++kk) {
        const f4 alo = *(const f4*)(ap + kk * 32);
        const f4 ahi = *(const f4*)(ap + kk * 32 + 4);
        const f4 blo = *(const f4*)(wp + kk * 32);
        const f4 bhi = *(const f4*)(wp + kk * 32 + 4);
        s8 af, bf;
        af[0] = bf16_rne(alo.x); af[1] = bf16_rne(alo.y);
        af[2] = bf16_rne(alo.z); af[3] = bf16_rne(alo.w);
        af[4] = bf16_rne(ahi.x); af[5] = bf16_rne(ahi.y);
        af[6] = bf16_rne(ahi.z); af[7] = bf16_rne(ahi.w);
        bf[0] = bf16_rne(blo.x); bf[1] = bf16_rne(blo.y);
        bf[2] = bf16_rne(blo.z); bf[3] = bf16_rne(blo.w);
        bf[4] = bf16_rne(bhi.x); bf[5] = bf16_rne(bhi.y);
        bf[6] = bf16_rne(bhi.z); bf[7] = bf16_rne(bhi.w);
        acc = __builtin_amdgcn_mfma_f32_16x16x32_bf16(af, bf, acc, 0, 0, 0);
    }

    // C/D layout (m89-verified): col = l&15, row = (l>>4)*4 + q
    #pragma unroll
    for (int q = 0; q < 4; ++q)
        Y[(m0 + g * 4 + q) * 512 + o0 + rc] = acc[q];
}

// R9's diagnostic body with plain stores: 1024 blocks, 5 identical passes.
__global__ __launch_bounds__(256) void pair_add(const f4* __restrict__ Y4,
                                                const f4* __restrict__ b4,
                                                f4* __restrict__ out4) {
    const int blk = blockIdx.x;          // b*128 + i, 0..1023
    const int t   = threadIdx.x;
    const int o4  = t & 127;             // 0..127 (128 f4 per row)
    const int jh  = t >> 7;              // 0 or 1

    const f4 yib = Y4[blk * 128 + o4] + b4[o4];
    const f4* __restrict__ Yb = Y4 + (blk >> 7) * (128 * 128);
    f4* __restrict__ orow = out4 + blk * (128 * 128);

    #pragma unroll 1
    for (int p = 0; p < 5; ++p) {
        #pragma unroll 4
        for (int j = jh; j < 128; j += 2) {
            orow[j * 128 + o4] = yib + Yb[j * 128 + o4];
        }
        asm volatile("" ::: "memory");
    }
}

extern "C" void kernel_launch(void* const* d_in, const int* in_sizes, int n_in,
                              void* d_out, int out_size, void* d_ws, size_t ws_size,
                              hipStream_t stream) {
    const float* L = (const float*)d_in[0];   // [8,128,512]
    const float* W = (const float*)d_in[1];   // [512,512]
    const float* b = (const float*)d_in[2];   // [512]
    float* out = (float*)d_out;               // [8,128,128,512]
    float* Y   = (float*)d_ws;                // [1024,512] scratch, 2 MiB

    gemm_mfma<<<dim3(32, 16), 256, 0, stream>>>(L, W, Y);
    pair_add<<<1024, 256, 0, stream>>>((const f4*)Y, (const f4*)b, (f4*)out);
    (void)in_sizes; (void)n_in; (void)out_size; (void)ws_size;
}

// Round 13
// 71.353 us; speedup vs baseline: 3.1569x; 3.1569x over previous
//
#include <hip/hip_runtime.h>
#include <hip/hip_bf16.h>

// out[b,i,j,o] = Y'[b*128+i][o] + Y'[b*128+j][o]
// where Y'[m][o] = sum_h L[m][h] * W[o][h] + 0.5*bias[o]   (M=1024, O=512, H=512)

typedef float f4    __attribute__((ext_vector_type(4)));
typedef short s8    __attribute__((ext_vector_type(8)));   // 8 bf16 (4 VGPRs)
typedef float f32x4 __attribute__((ext_vector_type(4)));

static __device__ __forceinline__ short bf16_rne(float f) {
    unsigned u = __builtin_bit_cast(unsigned, f);
    u += 0x7FFFu + ((u >> 16) & 1u);
    return (short)(u >> 16);
}

// Pre-touch: one dword store per 4KB page of out (65536 pages). Pre-walks
// the output's address translations (~2us) so pair_add's 268MB store stream
// hits warm TLBs (R12: passes 2-5 ran at 7.2 TB/s vs pass 1's 4.3).
__global__ __launch_bounds__(256) void touch_out(float* __restrict__ out) {
    const int p = blockIdx.x * 256 + threadIdx.x;   // 0..65535
    out[(size_t)p * 1024] = 0.0f;
}

// LDS-free MFMA GEMM: 512 blocks x 4 waves; each wave owns one 16x16 Y-tile.
// Epilogue folds 0.5*bias so pair_add needs no bias load.
__global__ __launch_bounds__(256) void gemm_mfma(const float* __restrict__ A,
                                                 const float* __restrict__ W,
                                                 const float* __restrict__ bias,
                                                 float* __restrict__ Y) {
    const int tid = threadIdx.x;
    const int w = tid >> 6;          // wave 0..3
    const int l = tid & 63;
    const int rc = l & 15;           // A-row / B-col / C-col
    const int g  = l >> 4;           // k-group (8 floats each)
    const int m0 = blockIdx.x * 32 + (w >> 1) * 16;   // gridDim.x = 32
    const int o0 = blockIdx.y * 32 + (w & 1) * 16;    // gridDim.y = 16

    const float* __restrict__ ap = A + (m0 + rc) * 512 + g * 8;
    const float* __restrict__ wp = W + (o0 + rc) * 512 + g * 8;

    f32x4 acc = {0.f, 0.f, 0.f, 0.f};

    #pragma unroll 4
    for (int kk = 0; kk < 16; ++kk) {
        const f4 alo = *(const f4*)(ap + kk * 32);
        const f4 ahi = *(const f4*)(ap + kk * 32 + 4);
        const f4 blo = *(const f4*)(wp + kk * 32);
        const f4 bhi = *(const f4*)(wp + kk * 32 + 4);
        s8 af, bf;
        af[0] = bf16_rne(alo.x); af[1] = bf16_rne(alo.y);
        af[2] = bf16_rne(alo.z); af[3] = bf16_rne(alo.w);
        af[4] = bf16_rne(ahi.x); af[5] = bf16_rne(ahi.y);
        af[6] = bf16_rne(ahi.z); af[7] = bf16_rne(ahi.w);
        bf[0] = bf16_rne(blo.x); bf[1] = bf16_rne(blo.y);
        bf[2] = bf16_rne(blo.z); bf[3] = bf16_rne(blo.w);
        bf[4] = bf16_rne(bhi.x); bf[5] = bf16_rne(bhi.y);
        bf[6] = bf16_rne(bhi.z); bf[7] = bf16_rne(bhi.w);
        acc = __builtin_amdgcn_mfma_f32_16x16x32_bf16(af, bf, acc, 0, 0, 0);
    }

    const float hb = 0.5f * bias[o0 + rc];
    // C/D layout (m89-verified): col = l&15, row = (l>>4)*4 + q
    #pragma unroll
    for (int q = 0; q < 4; ++q)
        Y[(m0 + g * 4 + q) * 512 + o0 + rc] = acc[q] + hb;
}

// One block per (b,i): 256KB contiguous. Plain stores (R10: NT costs +6.4us).
__global__ __launch_bounds__(256) void pair_add(const f4* __restrict__ Y4,
                                                f4* __restrict__ out4) {
    const int blk = blockIdx.x;          // b*128 + i, 0..1023
    const int t   = threadIdx.x;
    const int o4  = t & 127;             // 0..127 (128 f4 per row)
    const int jh  = t >> 7;              // 0 or 1

    const f4 yib = Y4[blk * 128 + o4];
    const f4* __restrict__ Yb = Y4 + (blk >> 7) * (128 * 128);
    f4* __restrict__ orow = out4 + blk * (128 * 128);

    #pragma unroll 4
    for (int j = jh; j < 128; j += 2) {
        orow[j * 128 + o4] = yib + Yb[j * 128 + o4];
    }
}

extern "C" void kernel_launch(void* const* d_in, const int* in_sizes, int n_in,
                              void* d_out, int out_size, void* d_ws, size_t ws_size,
                              hipStream_t stream) {
    const float* L = (const float*)d_in[0];   // [8,128,512]
    const float* W = (const float*)d_in[1];   // [512,512]
    const float* b = (const float*)d_in[2];   // [512]
    float* out = (float*)d_out;               // [8,128,128,512]
    float* Y   = (float*)d_ws;                // [1024,512] scratch, 2 MiB

    touch_out<<<256, 256, 0, stream>>>(out);
    gemm_mfma<<<dim3(32, 16), 256, 0, stream>>>(L, W, b, Y);
    pair_add<<<1024, 256, 0, stream>>>((const f4*)Y, (f4*)out);
    (void)in_sizes; (void)n_in; (void)out_size; (void)ws_size;
}

// Round 14
// 67.458 us; speedup vs baseline: 3.3392x; 1.0577x over previous
//
#include <hip/hip_runtime.h>
#include <hip/hip_bf16.h>

// out[b,i,j,o] = Y'[b*128+i][o] + Y'[b*128+j][o]
// where Y'[m][o] = sum_h L[m][h] * W[o][h] + 0.5*bias[o]   (M=1024, O=512, H=512)

typedef float f4    __attribute__((ext_vector_type(4)));
typedef short s8    __attribute__((ext_vector_type(8)));   // 8 bf16 (4 VGPRs)
typedef float f32x4 __attribute__((ext_vector_type(4)));

static __device__ __forceinline__ short bf16_rne(float f) {
    unsigned u = __builtin_bit_cast(unsigned, f);
    u += 0x7FFFu + ((u >> 16) & 1u);
    return (short)(u >> 16);
}

// LDS-free MFMA GEMM: 512 blocks x 4 waves; each wave owns one 16x16 Y-tile.
// Epilogue folds 0.5*bias. (R9: gemm+launch = 3.4us total.)
__global__ __launch_bounds__(256) void gemm_mfma(const float* __restrict__ A,
                                                 const float* __restrict__ W,
                                                 const float* __restrict__ bias,
                                                 float* __restrict__ Y) {
    const int tid = threadIdx.x;
    const int w = tid >> 6;          // wave 0..3
    const int l = tid & 63;
    const int rc = l & 15;           // A-row / B-col / C-col
    const int g  = l >> 4;           // k-group (8 floats each)
    const int m0 = blockIdx.x * 32 + (w >> 1) * 16;   // gridDim.x = 32
    const int o0 = blockIdx.y * 32 + (w & 1) * 16;    // gridDim.y = 16

    const float* __restrict__ ap = A + (m0 + rc) * 512 + g * 8;
    const float* __restrict__ wp = W + (o0 + rc) * 512 + g * 8;

    f32x4 acc = {0.f, 0.f, 0.f, 0.f};

    #pragma unroll 4
    for (int kk = 0; kk < 16; ++kk) {
        const f4 alo = *(const f4*)(ap + kk * 32);
        const f4 ahi = *(const f4*)(ap + kk * 32 + 4);
        const f4 blo = *(const f4*)(wp + kk * 32);
        const f4 bhi = *(const f4*)(wp + kk * 32 + 4);
        s8 af, bf;
        af[0] = bf16_rne(alo.x); af[1] = bf16_rne(alo.y);
        af[2] = bf16_rne(alo.z); af[3] = bf16_rne(alo.w);
        af[4] = bf16_rne(ahi.x); af[5] = bf16_rne(ahi.y);
        af[6] = bf16_rne(ahi.z); af[7] = bf16_rne(ahi.w);
        bf[0] = bf16_rne(blo.x); bf[1] = bf16_rne(blo.y);
        bf[2] = bf16_rne(blo.z); bf[3] = bf16_rne(blo.w);
        bf[4] = bf16_rne(bhi.x); bf[5] = bf16_rne(bhi.y);
        bf[6] = bf16_rne(bhi.z); bf[7] = bf16_rne(bhi.w);
        acc = __builtin_amdgcn_mfma_f32_16x16x32_bf16(af, bf, acc, 0, 0, 0);
    }

    const float hb = 0.5f * bias[o0 + rc];
    // C/D layout (m89-verified): col = l&15, row = (l>>4)*4 + q
    #pragma unroll
    for (int q = 0; q < 4; ++q)
        Y[(m0 + g * 4 + q) * 512 + o0 + rc] = acc[q] + hb;
}

// Warm Y into every XCD's L2 (and L3): 64 blocks; block bid reads slice
// bid>>3 (256KB); with bid%8 -> XCD round-robin each XCD covers all 8 slices.
// Makes pair_add's reads cache-hits so its HBM stream is pure-write.
__global__ __launch_bounds__(256) void warm_y(const f4* __restrict__ Y4) {
    const int s = blockIdx.x >> 3;                 // slice 0..7
    const f4* __restrict__ p = Y4 + s * 16384 + threadIdx.x;
    f4 acc = {0.f, 0.f, 0.f, 0.f};
    #pragma unroll 8
    for (int it = 0; it < 64; ++it)
        acc += p[it * 256];
    asm volatile("" :: "v"(acc.x), "v"(acc.y), "v"(acc.z), "v"(acc.w));
}

// Fill-kernel-shaped writer: 256 blocks x 256 threads grid-striding the flat
// f4 index f = n*65536 + bid*256 + tid  ->  one contiguous 1-MiB frontier per
// step (the pattern the harness fill sustains 7 TB/s with). Per thread:
// o4 = f&127 and j = (f>>7)&127 are FIXED; row bi = f>>14 = 4n + (bid>>6).
// 2 cache-hit loads + 1 contiguous store per iteration.
__global__ __launch_bounds__(256) void pair_add(const f4* __restrict__ Y4,
                                                f4* __restrict__ out4) {
    const int tid = threadIdx.x;
    const int bid = blockIdx.x;
    const int o4  = tid & 127;
    const int j   = ((bid << 1) + (tid >> 7)) & 127;
    const int c   = bid >> 6;                      // 0..3

    const f4* __restrict__ yi = Y4 + c * 128 + o4; // row 4n+c: advance 512/iter
    f4* __restrict__ op = out4 + bid * 256 + tid;  // advance 65536/iter

    #pragma unroll 4
    for (int n = 0; n < 256; ++n) {
        const int bi = 4 * n + c;
        const f4 a  = yi[(size_t)n * 512];
        const f4 bb = Y4[(size_t)(((bi >> 7) << 7) + j) * 128 + o4];
        op[(size_t)n * 65536] = a + bb;
    }
}

extern "C" void kernel_launch(void* const* d_in, const int* in_sizes, int n_in,
                              void* d_out, int out_size, void* d_ws, size_t ws_size,
                              hipStream_t stream) {
    const float* L = (const float*)d_in[0];   // [8,128,512]
    const float* W = (const float*)d_in[1];   // [512,512]
    const float* b = (const float*)d_in[2];   // [512]
    float* out = (float*)d_out;               // [8,128,128,512]
    float* Y   = (float*)d_ws;                // [1024,512] scratch, 2 MiB

    gemm_mfma<<<dim3(32, 16), 256, 0, stream>>>(L, W, b, Y);
    warm_y<<<64, 256, 0, stream>>>((const f4*)Y);
    pair_add<<<256, 256, 0, stream>>>((const f4*)Y, (f4*)out);
    (void)in_sizes; (void)n_in; (void)out_size; (void)ws_size;
}

// Round 15
// 63.392 us; speedup vs baseline: 3.5533x; 1.0641x over previous
//
#include <hip/hip_runtime.h>
#include <hip/hip_bf16.h>

// out[b,i,j,o] = Y'[b*128+i][o] + Y'[b*128+j][o]
// where Y'[m][o] = sum_h L[m][h] * W[o][h] + 0.5*bias[o]   (M=1024, O=512, H=512)

typedef float f4    __attribute__((ext_vector_type(4)));
typedef short s8    __attribute__((ext_vector_type(8)));   // 8 bf16 (4 VGPRs)
typedef float f32x4 __attribute__((ext_vector_type(4)));

static __device__ __forceinline__ short bf16_rne(float f) {
    unsigned u = __builtin_bit_cast(unsigned, f);
    u += 0x7FFFu + ((u >> 16) & 1u);
    return (short)(u >> 16);
}

// LDS-free MFMA GEMM: 512 blocks x 4 waves; each wave owns one 16x16 Y-tile.
// Epilogue folds 0.5*bias. (R9: gemm+launch = 3.4us total.)
__global__ __launch_bounds__(256) void gemm_mfma(const float* __restrict__ A,
                                                 const float* __restrict__ W,
                                                 const float* __restrict__ bias,
                                                 float* __restrict__ Y) {
    const int tid = threadIdx.x;
    const int w = tid >> 6;          // wave 0..3
    const int l = tid & 63;
    const int rc = l & 15;           // A-row / B-col / C-col
    const int g  = l >> 4;           // k-group (8 floats each)
    const int m0 = blockIdx.x * 32 + (w >> 1) * 16;   // gridDim.x = 32
    const int o0 = blockIdx.y * 32 + (w & 1) * 16;    // gridDim.y = 16

    const float* __restrict__ ap = A + (m0 + rc) * 512 + g * 8;
    const float* __restrict__ wp = W + (o0 + rc) * 512 + g * 8;

    f32x4 acc = {0.f, 0.f, 0.f, 0.f};

    #pragma unroll 4
    for (int kk = 0; kk < 16; ++kk) {
        const f4 alo = *(const f4*)(ap + kk * 32);
        const f4 ahi = *(const f4*)(ap + kk * 32 + 4);
        const f4 blo = *(const f4*)(wp + kk * 32);
        const f4 bhi = *(const f4*)(wp + kk * 32 + 4);
        s8 af, bf;
        af[0] = bf16_rne(alo.x); af[1] = bf16_rne(alo.y);
        af[2] = bf16_rne(alo.z); af[3] = bf16_rne(alo.w);
        af[4] = bf16_rne(ahi.x); af[5] = bf16_rne(ahi.y);
        af[6] = bf16_rne(ahi.z); af[7] = bf16_rne(ahi.w);
        bf[0] = bf16_rne(blo.x); bf[1] = bf16_rne(blo.y);
        bf[2] = bf16_rne(blo.z); bf[3] = bf16_rne(blo.w);
        bf[4] = bf16_rne(bhi.x); bf[5] = bf16_rne(bhi.y);
        bf[6] = bf16_rne(bhi.z); bf[7] = bf16_rne(bhi.w);
        acc = __builtin_amdgcn_mfma_f32_16x16x32_bf16(af, bf, acc, 0, 0, 0);
    }

    const float hb = 0.5f * bias[o0 + rc];
    // C/D layout (m89-verified): col = l&15, row = (l>>4)*4 + q
    #pragma unroll
    for (int q = 0; q < 4; ++q)
        Y[(m0 + g * 4 + q) * 512 + o0 + rc] = acc[q] + hb;
}

// Block = (b, 4 i-rows, 32 j-rows). Stage the 32 j-rows into LDS (64 KB) in
// one pipelined burst + 4 i-rows into registers; then the store loop is
// ds_read + add + global store ONLY — zero vmem reads threaded through the
// store storm (R12: identical loop runs 7.2 TB/s when reads don't leave the
// CU; pass-1 cost was fabric reads poisoning the write pipeline).
__global__ __launch_bounds__(256) void pair_add(const f4* __restrict__ Y4,
                                                f4* __restrict__ out4) {
    __shared__ __align__(16) f4 yj[32 * 128];   // 64 KB
    const int blk = blockIdx.x;          // 0..1023
    const int b   = blk >> 7;            // 0..7
    const int r   = blk & 127;
    const int i0  = (r >> 2) * 4;        // 0,4,...,124
    const int j0  = (r & 3) * 32;        // 0,32,64,96
    const int t   = threadIdx.x;
    const int o4  = t & 127;
    const int jh  = t >> 7;              // 0 or 1

    const f4* __restrict__ Yb = Y4 + b * (128 * 128);

    // stage: 32 rows x 128 f4 = 4096 f4, 16 per thread, coalesced
    #pragma unroll
    for (int k = 0; k < 16; ++k) {
        const int idx = t + k * 256;
        yj[idx] = Yb[(size_t)(j0 + (idx >> 7)) * 128 + (idx & 127)];
    }
    f4 yi[4];
    #pragma unroll
    for (int ii = 0; ii < 4; ++ii)
        yi[ii] = Yb[(size_t)(i0 + ii) * 128 + o4];
    __syncthreads();

    f4* __restrict__ ob = out4 + ((size_t)(b * 128 + i0) * 128 + j0) * 128;

    #pragma unroll 4
    for (int jj = 0; jj < 16; ++jj) {
        const int j = 2 * jj + jh;
        const f4 v = yj[j * 128 + o4];
        #pragma unroll
        for (int ii = 0; ii < 4; ++ii)
            ob[((size_t)ii * 128 + j) * 128 + o4] = yi[ii] + v;
    }
}

extern "C" void kernel_launch(void* const* d_in, const int* in_sizes, int n_in,
                              void* d_out, int out_size, void* d_ws, size_t ws_size,
                              hipStream_t stream) {
    const float* L = (const float*)d_in[0];   // [8,128,512]
    const float* W = (const float*)d_in[1];   // [512,512]
    const float* b = (const float*)d_in[2];   // [512]
    float* out = (float*)d_out;               // [8,128,128,512]
    float* Y   = (float*)d_ws;                // [1024,512] scratch, 2 MiB

    gemm_mfma<<<dim3(32, 16), 256, 0, stream>>>(L, W, b, Y);
    pair_add<<<1024, 256, 0, stream>>>((const f4*)Y, (f4*)out);
    (void)in_sizes; (void)n_in; (void)out_size; (void)ws_size;
}